// Round 6
// baseline (487.951 us; speedup 1.0000x reference)
//
#include <hip/hip_runtime.h>

#define CH_N 64
#define HH 128
#define WW 128
#define BB 8
#define HW (HH*WW)

// ---------------- BN stats: per-channel partial sums (atomics) ----------------
__global__ __launch_bounds__(256) void k_stats(const float* __restrict__ xL,
                                               const float* __restrict__ xR,
                                               float* __restrict__ sums) {
  int blk = blockIdx.x;                 // 512 blocks: img(2) x c(64) x slice(4)
  int img = blk >> 8, c = (blk >> 2) & 63, s = blk & 3;
  const float* x = img ? xR : xL;
  float sm = 0.f, sq = 0.f;
  for (int n = 2*s; n < 2*s+2; ++n) {
    const float4* p = (const float4*)(x + ((size_t)(n*64+c))*HW);
    for (int i = threadIdx.x; i < 4096; i += 256) {
      float4 v = p[i];
      sm += (v.x+v.y)+(v.z+v.w);
      sq += (v.x*v.x+v.y*v.y)+(v.z*v.z+v.w*v.w);
    }
  }
  #pragma unroll
  for (int o = 32; o > 0; o >>= 1) { sm += __shfl_down(sm, o); sq += __shfl_down(sq, o); }
  __shared__ float rs[2][4];
  int wid = threadIdx.x >> 6;
  if ((threadIdx.x & 63) == 0) { rs[0][wid] = sm; rs[1][wid] = sq; }
  __syncthreads();
  if (threadIdx.x == 0) {
    sm = (rs[0][0]+rs[0][1])+(rs[0][2]+rs[0][3]);
    sq = (rs[1][0]+rs[1][1])+(rs[1][2]+rs[1][3]);
    atomicAdd(&sums[(img*64+c)*2+0], sm);
    atomicAdd(&sums[(img*64+c)*2+1], sq);
  }
}

__global__ __launch_bounds__(128) void k_finalize(const float* __restrict__ sums,
                                                  const float* __restrict__ gamma,
                                                  const float* __restrict__ beta,
                                                  float* __restrict__ ss) {
  int t = threadIdx.x;
  if (t < 128) {
    int c = t & 63;
    float sm = sums[t*2], sq = sums[t*2+1];
    float mean = sm * (1.f/131072.f);
    float var  = sq * (1.f/131072.f) - mean*mean;
    float scale = gamma[c] * rsqrtf(var + 1e-5f);
    ss[t*2+0] = scale;
    ss[t*2+1] = beta[c] - mean*scale;
  }
}

// ---------------- grouped 3x3 conv, pad=1 ----------------
// MODE 0 (dual-image, z=16): y = lrelu(conv(BN(in)))      -> out = y1
// MODE 1 (single-image, z=8): y2 = conv(in) + BN(xres);
//         fused 1x1 -> out = Q/K = qw*y2 + qb, plus per-(b,c,h) row sums.
// XCD-slice swizzle: all 64 tiles of one (g,nz) slice land on one XCD so halo
// cache lines (the neighbor tile's interior) hit that XCD's L2 instead of HBM.
// LDS (floats), conflict-audited layouts:
//   in_t : ic*364 + ry*20 + (x_local+4); interior aligned ds_write/read_b128.
//   w_t  : WOFF + oc*200 + ic*12 + k     (200 mod 32 = 8 -> oc groups spread)
//   MODE1 reuse: y2_t oc*328 + py*20 + px ; qw_t WOFF+oc*16+ic ; qb_t QBOFF+oc
#define WOFF  5824
#define QBOFF (WOFF + 256)

template<int MODE>
__global__ __launch_bounds__(256, 4) void k_conv(
    const float* __restrict__ inL, const float* __restrict__ inR,
    const float* __restrict__ xresL, const float* __restrict__ xresR,
    const float* __restrict__ w, const float* __restrict__ bias,
    const float* __restrict__ ss,
    float* __restrict__ outL_, float* __restrict__ outR_,
    const float* __restrict__ qwL, const float* __restrict__ qbL,
    float* __restrict__ rsL) {
  __shared__ float smem[9024];
  // ---- bijective XCD-slice swizzle (gridDim.x=64, gridDim.y=4) ----
  int l = blockIdx.x + (blockIdx.y << 6) + (blockIdx.z << 8);
  int spx = (gridDim.y * gridDim.z) >> 3;    // slices per XCD (8 or 4)
  int jj = l >> 3;
  int tile = jj & 63;
  int slice = (l & 7) * spx + (jj >> 6);
  int g = slice & 3;
  int nz = slice >> 2;

  int img = nz >> 3, n = nz & 7;             // z=8 launches: img==0 always
  const float* in   = img ? inR : inL;
  const float* xres = img ? xresR : xresL;
  const float* ssp  = ss + img*128;
  float* out        = img ? outR_ : outL_;
  const float* qw1  = qwL;
  const float* qb1  = qbL;
  float* rowsum     = rsL;

  int x0 = (tile & 7) << 4, y0 = (tile >> 3) << 4;
  int t = threadIdx.x;
  int n64 = n*64 + g*16;

  // ---- stage 3x3 weights: thread t -> (oc = t>>4, ic = t&15), 9 taps ----
  {
    int ocw = t >> 4, icw = t & 15;
    const float* wp = w + (size_t)(g*16 + ocw)*144 + icw*9;
    float* wd = &smem[WOFF + ocw*200 + icw*12];
    #pragma unroll
    for (int k = 0; k < 9; ++k) wd[k] = wp[k];
  }

  // ---- stage interior 16x16 per channel: aligned ds_write_b128 ----
  {
    int q = t & 3, ry = ((t >> 2) & 15) + 1, icb = t >> 6;   // icb 0..3
    int gy = y0 + ry - 1;                                    // in [0,127]
    const float* rowp = in + ((size_t)(n64 + icb)*128 + gy)*128 + x0 + (q << 2);
    float* dst = &smem[icb*364 + ry*20 + 4 + (q << 2)];
    #pragma unroll
    for (int k = 0; k < 4; ++k) {                            // ic = icb + 4k
      float4 v4 = *(const float4*)(rowp + (size_t)(4*k)*HW);
      if (MODE == 0) {
        int cc = (g*16 + icb + 4*k) * 2;
        float sA = ssp[cc], sB = ssp[cc+1];
        v4.x = fmaf(v4.x,sA,sB); v4.y = fmaf(v4.y,sA,sB);
        v4.z = fmaf(v4.z,sA,sB); v4.w = fmaf(v4.w,sA,sB);
      }
      *(float4*)(dst + 4*k*364) = v4;
    }
  }
  // ---- stage halo: left/right columns (t<64), top/bottom rows (64<=t<192) ----
  if (t < 64) {
    int side = t >> 5, lane = t & 31;
    int ic = lane >> 1, half = lane & 1;
    int gx = side ? x0 + 16 : x0 - 1;
    bool xok = ((unsigned)gx < 128u);
    int gxc = xok ? gx : 0;
    int col = side ? 20 : 3;          // x_local 16 -> 20, x_local -1 -> 3
    const float* base = in + (size_t)(n64 + ic)*HW;
    float sA = 0.f, sB = 0.f;
    if (MODE == 0) { int cc = (g*16+ic)*2; sA = ssp[cc]; sB = ssp[cc+1]; }
    #pragma unroll
    for (int k = 0; k < 9; ++k) {
      int r = half*9 + k;
      int gy = y0 - 1 + r;
      bool ok = xok && ((unsigned)gy < 128u);
      int gyc = ((unsigned)gy < 128u) ? gy : 0;
      float v = base[(size_t)gyc*128 + gxc];
      if (MODE == 0) v = fmaf(v, sA, sB);
      smem[ic*364 + r*20 + col] = ok ? v : 0.f;
    }
  } else if (t < 192) {
    int j = t - 64;
    int half = j >> 6, l2 = j & 63;
    int ic = l2 >> 2, q = l2 & 3;
    int gy = half ? y0 + 16 : y0 - 1;
    bool ok = ((unsigned)gy < 128u);
    int gyc = ok ? gy : 0;
    float4 v4 = *(const float4*)&in[((size_t)(n64 + ic)*128 + gyc)*128 + x0 + (q << 2)];
    if (MODE == 0) {
      int cc = (g*16+ic)*2;
      float sA = ssp[cc], sB = ssp[cc+1];
      v4.x = fmaf(v4.x,sA,sB); v4.y = fmaf(v4.y,sA,sB);
      v4.z = fmaf(v4.z,sA,sB); v4.w = fmaf(v4.w,sA,sB);
    }
    if (!ok) { v4.x = 0.f; v4.y = 0.f; v4.z = 0.f; v4.w = 0.f; }
    int ry = half ? 17 : 0;
    *(float4*)&smem[ic*364 + ry*20 + 4 + (q << 2)] = v4;
  }
  __syncthreads();

  int oc = t >> 4, sub = t & 15;
  int sy = (sub >> 2) << 2, sx = (sub & 3) << 2;
  int c = g*16 + oc;
  float acc[4][4];
  float bv = bias[c];
  #pragma unroll
  for (int i = 0; i < 4; ++i)
    #pragma unroll
    for (int j = 0; j < 4; ++j) acc[i][j] = bv;

  for (int ic = 0; ic < 16; ++ic) {
    const float* it = &smem[ic*364 + sy*20 + sx];
    float win[6][6];
    #pragma unroll
    for (int r = 0; r < 6; ++r) {
      const float* rp = it + r*20;
      float lw = rp[3];                           // x_local sx-1
      const float4 m4 = *(const float4*)(rp + 4); // x_local sx..sx+3 (aligned)
      float rw = rp[8];                           // x_local sx+4
      win[r][0]=lw; win[r][1]=m4.x; win[r][2]=m4.y;
      win[r][3]=m4.z; win[r][4]=m4.w; win[r][5]=rw;
    }
    const float4 w0 = *(const float4*)&smem[WOFF + oc*200 + ic*12];
    const float4 w1 = *(const float4*)&smem[WOFF + oc*200 + ic*12 + 4];
    const float  w8 = smem[WOFF + oc*200 + ic*12 + 8];
    float wv[9] = {w0.x,w0.y,w0.z,w0.w,w1.x,w1.y,w1.z,w1.w,w8};
    #pragma unroll
    for (int i = 0; i < 4; ++i)
      #pragma unroll
      for (int j = 0; j < 4; ++j) {
        float a = acc[i][j];
        #pragma unroll
        for (int ky = 0; ky < 3; ++ky)
          #pragma unroll
          for (int kx = 0; kx < 3; ++kx)
            a = fmaf(win[i+ky][j+kx], wv[ky*3+kx], a);
        acc[i][j] = a;
      }
  }

  if (MODE == 0) {
    #pragma unroll
    for (int i = 0; i < 4; ++i) {
      int oy = y0 + sy + i;
      size_t rowbase = ((size_t)(n*64+c)*128 + oy)*128;
      float4 o;
      o.x = acc[i][0] > 0.f ? acc[i][0] : 0.1f*acc[i][0];
      o.y = acc[i][1] > 0.f ? acc[i][1] : 0.1f*acc[i][1];
      o.z = acc[i][2] > 0.f ? acc[i][2] : 0.1f*acc[i][2];
      o.w = acc[i][3] > 0.f ? acc[i][3] : 0.1f*acc[i][3];
      *(float4*)&out[rowbase + x0 + sx] = o;
    }
  } else {
    // y2 = conv + BN(xres), stash in LDS (in_t + w_t regions are dead now)
    float sA = ssp[c*2], sB = ssp[c*2+1];
    __syncthreads();   // all in_t/w_t reads complete before aliasing
    #pragma unroll
    for (int i = 0; i < 4; ++i) {
      int oy = y0 + sy + i;
      size_t rowbase = ((size_t)(n*64+c)*128 + oy)*128;
      const float4 xr4 = *(const float4*)&xres[rowbase + x0 + sx];
      float4 v4;
      v4.x = acc[i][0] + fmaf(xr4.x, sA, sB);
      v4.y = acc[i][1] + fmaf(xr4.y, sA, sB);
      v4.z = acc[i][2] + fmaf(xr4.z, sA, sB);
      v4.w = acc[i][3] + fmaf(xr4.w, sA, sB);
      *(float4*)&smem[oc*328 + (sy+i)*20 + sx] = v4;
    }
    smem[WOFF + t] = qw1[g*256 + t];
    if (t < 16) smem[QBOFF + t] = qb1[g*16 + t];
    __syncthreads();

    float qa[4][4];
    float bq = smem[QBOFF + oc];
    #pragma unroll
    for (int i = 0; i < 4; ++i)
      #pragma unroll
      for (int j = 0; j < 4; ++j) qa[i][j] = bq;
    #pragma unroll 4
    for (int ic = 0; ic < 16; ++ic) {
      float wq = smem[WOFF + oc*16 + ic];
      #pragma unroll
      for (int i = 0; i < 4; ++i) {
        const float4 yv = *(const float4*)&smem[ic*328 + (sy+i)*20 + sx];
        qa[i][0] = fmaf(wq, yv.x, qa[i][0]);
        qa[i][1] = fmaf(wq, yv.y, qa[i][1]);
        qa[i][2] = fmaf(wq, yv.z, qa[i][2]);
        qa[i][3] = fmaf(wq, yv.w, qa[i][3]);
      }
    }
    #pragma unroll
    for (int i = 0; i < 4; ++i) {
      int oy = y0 + sy + i;
      size_t rowbase = ((size_t)(n*64+c)*128 + oy)*128;
      float4 o4 = make_float4(qa[i][0], qa[i][1], qa[i][2], qa[i][3]);
      *(float4*)&out[rowbase + x0 + sx] = o4;
      float r = (qa[i][0]+qa[i][1]) + (qa[i][2]+qa[i][3]);
      r += __shfl_xor(r, 1);
      r += __shfl_xor(r, 2);
      if ((t & 3) == 0) atomicAdd(&rowsum[(size_t)(n*64+c)*128 + oy], r);
    }
  }
}

// ---------------- PAM core: one block per (b,h) row, ~78 KB LDS -> 2 blk/CU ----
// Q/K arrive WITHOUT mean subtraction; P1 subtracts rowsum/128 at stage time.
// Q (B2) and K (B0) are distinct workspace buffers -> full __restrict__.
__device__ __forceinline__ int SW(int r, int c) {
  return (r << 7) + (((c >> 2) ^ (r & 31)) << 2) + (c & 3);
}
__device__ __forceinline__ int SWQ(int r, int q) {
  return (r << 7) + ((q ^ (r & 31)) << 2);
}

__global__ __launch_bounds__(512, 4) void k_pam(const float* __restrict__ Q,
                                                const float* __restrict__ K,
                                                const float* __restrict__ XL,
                                                const float* __restrict__ XR,
                                                float* __restrict__ outL,
                                                float* __restrict__ outR,
                                                const float* __restrict__ rsL,
                                                const float* __restrict__ rsR) {
  extern __shared__ float smp[];
  float* ST   = smp;            // 16384 floats, swizzled score -> M_rl
  float* CHB  = smp + 16384;    // 2048 floats: QK chunks / x chunks / scratch
  float* rmax = smp + 18432;
  float* rinv = rmax + 128;
  float* cmax = rmax + 256;
  float* cinv = rmax + 384;
  float* Vl   = rmax + 512;
  float* Vr   = rmax + 640;
  float* Pu   = rmax + 768;
  float* Qv   = rmax + 896;
  float* ms   = rmax + 1024;    // [0] = global max
  float* pm   = CHB;            // P2/P3 partial scratch overlaps chunk buffer
  float* pl   = CHB + 512;
  float* pm2  = CHB + 1024;
  float* pl2  = CHB + 1536;

  int t = threadIdx.x;
  int b = blockIdx.x >> 7, h = blockIdx.x & 127;
  size_t qbase = ((size_t)(b*64)*128 + h)*128;   // + c*HW + u

  // ---- P1: score -> ST (swizzled); chunk loads prefetched into registers ----
  {
    int u0 = (t & 31) << 2, v0 = (t >> 5) << 3;
    float a0[8], a1[8], a2[8], a3[8];
    #pragma unroll
    for (int j = 0; j < 8; ++j) { a0[j]=0.f; a1[j]=0.f; a2[j]=0.f; a3[j]=0.f; }
    int half = t >> 8;               // 0 = Q, 1 = K
    int cl_ld = (t >> 5) & 7;
    int u4_ld = (t & 31) << 2;
    const float* src = half ? K : Q;
    const float* rsum = half ? rsR : rsL;
    // prefetch chunk 0
    float mean = rsum[((size_t)b*64 + cl_ld)*128 + h] * (1.f/128.f);
    float4 v = *(const float4*)&src[qbase + (size_t)cl_ld*HW + u4_ld];
    for (int cb = 0; cb < 8; ++cb) {
      __syncthreads();   // previous chunk fully consumed
      v.x -= mean; v.y -= mean; v.z -= mean; v.w -= mean;
      *(float4*)&CHB[half*1024 + cl_ld*128 + u4_ld] = v;
      if (cb < 7) {      // issue next chunk's loads; latency hides under FMAs
        mean = rsum[((size_t)b*64 + (cb+1)*8 + cl_ld)*128 + h] * (1.f/128.f);
        v = *(const float4*)&src[qbase + (size_t)((cb+1)*8 + cl_ld)*HW + u4_ld];
      }
      __syncthreads();
      #pragma unroll
      for (int cl = 0; cl < 8; ++cl) {
        const float4 qv = *(const float4*)&CHB[cl*128 + u0];
        const float4 k0 = *(const float4*)&CHB[1024 + cl*128 + v0];
        const float4 k1 = *(const float4*)&CHB[1024 + cl*128 + v0 + 4];
        float kk[8] = {k0.x,k0.y,k0.z,k0.w,k1.x,k1.y,k1.z,k1.w};
        #pragma unroll
        for (int j = 0; j < 8; ++j) {
          float kv = kk[j];
          a0[j] = fmaf(qv.x, kv, a0[j]);
          a1[j] = fmaf(qv.y, kv, a1[j]);
          a2[j] = fmaf(qv.z, kv, a2[j]);
          a3[j] = fmaf(qv.w, kv, a3[j]);
        }
      }
    }
    #pragma unroll
    for (int j = 0; j < 8; ++j) {
      int r = v0 + j;
      *(float4*)&ST[SWQ(r, u0 >> 2)] = make_float4(a0[j], a1[j], a2[j], a3[j]);
    }
  }
  __syncthreads();

  // ---- P2: row stats (over v, fixed u) + col stats (over u, fixed v) ----
  {
    int u = t & 127, q = t >> 7, vb = q << 5;
    float m = -1e30f;
    for (int v = vb; v < vb+32; ++v) m = fmaxf(m, ST[SW(v, u)]);
    float l = 0.f;
    for (int v = vb; v < vb+32; ++v) l += __expf(ST[SW(v, u)] - m);
    float m2 = -1e30f;
    for (int k = (vb >> 2); k < (vb >> 2) + 8; ++k) {
      const float4 x4 = *(const float4*)&ST[SWQ(u, k)];
      m2 = fmaxf(m2, fmaxf(fmaxf(x4.x, x4.y), fmaxf(x4.z, x4.w)));
    }
    float l2 = 0.f;
    for (int k = (vb >> 2); k < (vb >> 2) + 8; ++k) {
      const float4 x4 = *(const float4*)&ST[SWQ(u, k)];
      l2 += (__expf(x4.x-m2)+__expf(x4.y-m2)) + (__expf(x4.z-m2)+__expf(x4.w-m2));
    }
    pm[t] = m; pl[t] = l;
    pm2[t] = m2; pl2[t] = l2;
  }
  __syncthreads();
  if (t < 256) {
    int u = t & 127;
    const float* PM = (t < 128) ? pm : pm2;
    const float* PL = (t < 128) ? pl : pl2;
    float m = fmaxf(fmaxf(PM[u], PM[128+u]), fmaxf(PM[256+u], PM[384+u]));
    float l = PL[u]*__expf(PM[u]-m) + PL[128+u]*__expf(PM[128+u]-m)
            + PL[256+u]*__expf(PM[256+u]-m) + PL[384+u]*__expf(PM[384+u]-m);
    if (t < 128) { rmax[u] = m; rinv[u] = 1.f/l; }
    else         { cmax[u] = m; cinv[u] = 1.f/l; }
  }
  __syncthreads();

  // ---- global max m* (one wave) ----
  if (t < 64) {
    float m = fmaxf(rmax[t], rmax[t+64]);
    #pragma unroll
    for (int o = 32; o > 0; o >>= 1) m = fmaxf(m, __shfl_down(m, o));
    if (t == 0) ms[0] = m;
  }
  __syncthreads();

  // ---- Pu/Qv + in-place transform ST -> M_rl ----
  {
    float ms0 = ms[0];
    if (t < 128)      Pu[t] = __expf(rmax[t] - ms0) / rinv[t];
    else if (t < 256) { int v = t - 128; Qv[v] = __expf(ms0 - cmax[v]) * cinv[v]; }
    int u = t & 127, q = t >> 7;
    float ru = rmax[u], ri = rinv[u];
    for (int v = (q << 5); v < (q << 5) + 32; ++v) {
      int a = SW(v, u);
      ST[a] = __expf(ST[a] - ru) * ri;
    }
  }
  __syncthreads();

  // ---- P3: V partials (exp-free) ----
  {
    int u = t & 127, q = t >> 7, vb = q << 5;
    int rcl[5]; float wL[5], qvd[5];
    #pragma unroll
    for (int d = 0; d < 5; ++d) {
      int uu = u - 2 + d;
      bool ok = (uu >= 0 && uu < 128);
      rcl[d] = ok ? uu : u;
      wL[d]  = ok ? 1.f : 0.f;
      qvd[d] = ok ? Qv[uu] : 0.f;
    }
    float pu_u = Pu[u];
    float accL = 0.f, accR = 0.f;
    // accL: row-direction reads (conflict-free), plain v order
    for (int v = vb; v < vb+32; ++v) {
      float rr0 = ST[SW(v, rcl[0])], rr1 = ST[SW(v, rcl[1])];
      float rr2 = ST[SW(v, u)];
      float rr3 = ST[SW(v, rcl[3])], rr4 = ST[SW(v, rcl[4])];
      float R = rr2 + (wL[0]*rr0 + wL[1]*rr1) + (wL[3]*rr3 + wL[4]*rr4);
      accL = fmaf(R * rr2, Qv[v], accL);
    }
    accL *= pu_u;
    // accR: column-direction reads; per-lane bank-spread v order
    {
      int ush = u >> 3;
      #pragma unroll 2
      for (int a = 0; a < 8; ++a) {
        #pragma unroll
        for (int bq = 0; bq < 4; ++bq) {
          int v = vb + (a << 2) + ((bq + ush) & 3);
          float cc0 = ST[SW(rcl[0], v)], cc1 = ST[SW(rcl[1], v)];
          float cc2 = ST[SW(u, v)];
          float cc3 = ST[SW(rcl[3], v)], cc4 = ST[SW(rcl[4], v)];
          float G = cc2*qvd[2] + (cc0*qvd[0] + cc1*qvd[1]) + (cc3*qvd[3] + cc4*qvd[4]);
          accR = fmaf(G * cc2, Pu[v], accR);
        }
      }
    }
    __syncthreads();   // P2 combine readers done before overwriting pm/pl
    pm[t] = accL; pl[t] = accR;
  }
  __syncthreads();
  if (t < 128) {
    float vsL = pm[t]+pm[128+t]+pm[256+t]+pm[384+t];
    float vsR = pl[t]+pl[128+t]+pl[256+t]+pl[384+t];
    Vl[t] = tanhf(5.f*vsL);
    Vr[t] = tanhf(5.f*vsR);
  }

  int ul = t & 63, c0 = (t >> 6) << 3;
  int c_ld = t >> 3, q_ld = (t & 7) << 2;     // chunk load: c 0..63, 4 v's
  int csw_st = c_ld ^ (((q_ld >> 2) & 7) << 3);   // swizzled staging column

  // ---- P5: out_left = xl*(1-Vl) + (M_rl @ xr)*Vl, xr in 8 KB v-chunks ----
  {
    float acc0[8], acc1[8];
    #pragma unroll
    for (int j = 0; j < 8; ++j) { acc0[j]=0.f; acc1[j]=0.f; }
    float4 r4 = *(const float4*)&XR[qbase + (size_t)c_ld*HW + q_ld];  // chunk 0
    for (int cb = 0; cb < 4; ++cb) {
      __syncthreads();   // prev chunk consumed (and Vl/Vr readers done)
      CHB[(q_ld+0)*64+csw_st] = r4.x; CHB[(q_ld+1)*64+csw_st] = r4.y;
      CHB[(q_ld+2)*64+csw_st] = r4.z; CHB[(q_ld+3)*64+csw_st] = r4.w;
      if (cb < 3)
        r4 = *(const float4*)&XR[qbase + (size_t)c_ld*HW + ((cb+1) << 5) + q_ld];
      __syncthreads();
      int vb = cb << 5;
      for (int vv = 0; vv < 32; ++vv) {
        int v = vb + vv;
        float m0 = ST[SW(v, ul)];
        float m1 = ST[SW(v, ul+64)];
        int cs = c0 ^ (((vv >> 2) & 7) << 3);
        const float4 xa = *(const float4*)&CHB[vv*64 + cs];
        const float4 xb = *(const float4*)&CHB[vv*64 + cs + 4];
        acc0[0]=fmaf(m0,xa.x,acc0[0]); acc0[1]=fmaf(m0,xa.y,acc0[1]);
        acc0[2]=fmaf(m0,xa.z,acc0[2]); acc0[3]=fmaf(m0,xa.w,acc0[3]);
        acc0[4]=fmaf(m0,xb.x,acc0[4]); acc0[5]=fmaf(m0,xb.y,acc0[5]);
        acc0[6]=fmaf(m0,xb.z,acc0[6]); acc0[7]=fmaf(m0,xb.w,acc0[7]);
        acc1[0]=fmaf(m1,xa.x,acc1[0]); acc1[1]=fmaf(m1,xa.y,acc1[1]);
        acc1[2]=fmaf(m1,xa.z,acc1[2]); acc1[3]=fmaf(m1,xa.w,acc1[3]);
        acc1[4]=fmaf(m1,xb.x,acc1[4]); acc1[5]=fmaf(m1,xb.y,acc1[5]);
        acc1[6]=fmaf(m1,xb.z,acc1[6]); acc1[7]=fmaf(m1,xb.w,acc1[7]);
      }
    }
    float vl0 = Vl[ul], vl1 = Vl[ul+64];
    #pragma unroll
    for (int j = 0; j < 8; ++j) {
      size_t o0 = qbase + (size_t)(c0+j)*HW + ul;
      outL[o0]    = XL[o0]   *(1.f-vl0) + acc0[j]*vl0;
      outL[o0+64] = XL[o0+64]*(1.f-vl1) + acc1[j]*vl1;
    }
  }

  // ---- P6: out_right = xr*(1-Vr) + (M_lr @ xl)*Vr, xl in 8 KB v-chunks ----
  // M_lr[u,v] = ST[SW(u,v)] * Pu[v] * Qv[u]
  {
    float acc0[8], acc1[8];
    #pragma unroll
    for (int j = 0; j < 8; ++j) { acc0[j]=0.f; acc1[j]=0.f; }
    float qv_u0 = Qv[ul], qv_u1 = Qv[ul+64];
    float4 r4 = *(const float4*)&XL[qbase + (size_t)c_ld*HW + q_ld];  // chunk 0
    for (int cb = 0; cb < 4; ++cb) {
      __syncthreads();
      CHB[(q_ld+0)*64+csw_st] = r4.x; CHB[(q_ld+1)*64+csw_st] = r4.y;
      CHB[(q_ld+2)*64+csw_st] = r4.z; CHB[(q_ld+3)*64+csw_st] = r4.w;
      if (cb < 3)
        r4 = *(const float4*)&XL[qbase + (size_t)c_ld*HW + ((cb+1) << 5) + q_ld];
      __syncthreads();
      int qb = cb << 3;
      for (int lq = 0; lq < 8; ++lq) {
        const float4 s0 = *(const float4*)&ST[SWQ(ul,    qb+lq)];
        const float4 s1 = *(const float4*)&ST[SWQ(ul+64, qb+lq)];
        const float4 pu4 = *(const float4*)&Pu[(qb+lq) << 2];
        float sv0[4] = {s0.x, s0.y, s0.z, s0.w};
        float sv1[4] = {s1.x, s1.y, s1.z, s1.w};
        float pv[4]  = {pu4.x, pu4.y, pu4.z, pu4.w};
        int cs = c0 ^ ((lq & 7) << 3);
        #pragma unroll
        for (int k = 0; k < 4; ++k) {
          float m0 = sv0[k] * pv[k] * qv_u0;
          float m1 = sv1[k] * pv[k] * qv_u1;
          const float4 xa0 = *(const float4*)&CHB[((lq<<2)+k)*64 + cs];
          const float4 xb0 = *(const float4*)&CHB[((lq<<2)+k)*64 + cs + 4];
          acc0[0]=fmaf(m0,xa0.x,acc0[0]); acc0[1]=fmaf(m0,xa0.y,acc0[1]);
          acc0[2]=fmaf(m0,xa0.z,acc0[2]); acc0[3]=fmaf(m0,xa0.w,acc0[3]);
          acc0[4]=fmaf(m0,xb0.x,acc0[4]); acc0[5]=fmaf(m0,xb0.y,acc0[5]);
          acc0[6]=fmaf(m0,xb0.z,acc0[6]); acc0[7]=fmaf(m0,xb0.w,acc0[7]);
          acc1[0]=fmaf(m1,xa0.x,acc1[0]); acc1[1]=fmaf(m1,xa0.y,acc1[1]);
          acc1[2]=fmaf(m1,xa0.z,acc1[2]); acc1[3]=fmaf(m1,xa0.w,acc1[3]);
          acc1[4]=fmaf(m1,xb0.x,acc1[4]); acc1[5]=fmaf(m1,xb0.y,acc1[5]);
          acc1[6]=fmaf(m1,xb0.z,acc1[6]); acc1[7]=fmaf(m1,xb0.w,acc1[7]);
        }
      }
    }
    float vr0 = Vr[ul], vr1 = Vr[ul+64];
    #pragma unroll
    for (int j = 0; j < 8; ++j) {
      size_t o0 = qbase + (size_t)(c0+j)*HW + ul;
      outR[o0]    = XR[o0]   *(1.f-vr0) + acc0[j]*vr0;
      outR[o0+64] = XR[o0+64]*(1.f-vr1) + acc1[j]*vr1;
    }
  }
}

extern "C" void kernel_launch(void* const* d_in, const int* in_sizes, int n_in,
                              void* d_out, int out_size, void* d_ws, size_t ws_size,
                              hipStream_t stream) {
  const float* xL    = (const float*)d_in[0];
  const float* xR    = (const float*)d_in[1];
  const float* gamma = (const float*)d_in[2];
  const float* beta  = (const float*)d_in[3];
  const float* rw1   = (const float*)d_in[4];
  const float* rb1   = (const float*)d_in[5];
  const float* rw2   = (const float*)d_in[6];
  const float* rb2   = (const float*)d_in[7];
  const float* qw    = (const float*)d_in[8];
  const float* qb    = (const float*)d_in[9];
  const float* kw    = (const float*)d_in[10];
  const float* kb    = (const float*)d_in[11];
  float* out = (float*)d_out;
  char* ws = (char*)d_ws;

  const size_t BUF = (size_t)BB*CH_N*HW*4;   // 33,554,432 bytes
  float* y1L  = (float*)(ws);                // B0: y1 left, later K
  float* y1R  = (float*)(ws + BUF);          // B1: y1 right
  float* Qb   = (float*)(ws + 2*BUF);        // B2: Q
  float* Kb   = y1L;                         // K overwrites dead y1L
  float* sums = (float*)(ws + 3*BUF);        // 256 floats
  float* ss   = sums + 256;                  // 256 floats
  float* rsL  = sums + 512;                  // 8*64*128 floats
  float* rsR  = rsL + (size_t)BB*CH_N*HH;

  hipMemsetAsync(sums, 0, (512 + 2*(size_t)BB*CH_N*HH)*sizeof(float), stream);
  k_stats<<<512, 256, 0, stream>>>(xL, xR, sums);
  k_finalize<<<1, 128, 0, stream>>>(sums, gamma, beta, ss);

  dim3 cg0(64, 4, 16);
  k_conv<0><<<cg0, 256, 0, stream>>>(xL, xR, xL, xR, rw1, rb1, ss, y1L, y1R,
                                     nullptr, nullptr, nullptr);
  dim3 cg1(64, 4, 8);
  // image L: y1L -> Q (B2)
  k_conv<1><<<cg1, 256, 0, stream>>>(y1L, nullptr, xL, nullptr, rw2, rb2, ss,
                                     Qb, nullptr, qw, qb, rsL);
  // image R: y1R -> K (B0; y1L dead after previous launch)
  k_conv<1><<<cg1, 256, 0, stream>>>(y1R, nullptr, xR, nullptr, rw2, rb2, ss + 128,
                                     Kb, nullptr, kw, kb, rsR);

  const int SMEM = 19464 * 4;   // 77,856 B -> 2 blocks/CU
  hipFuncSetAttribute((const void*)k_pam, hipFuncAttributeMaxDynamicSharedMemorySize, SMEM);
  k_pam<<<1024, 512, SMEM, stream>>>(Qb, Kb, xL, xR, out, out + (size_t)BB*CH_N*HW, rsL, rsR);
}

// Round 7
// 484.641 us; speedup vs baseline: 1.0068x; 1.0068x over previous
//
#include <hip/hip_runtime.h>

#define CH_N 64
#define HH 128
#define WW 128
#define BB 8
#define HW (HH*WW)

// ---------------- BN stats: per-channel partial sums (atomics) ----------------
__global__ __launch_bounds__(256) void k_stats(const float* __restrict__ xL,
                                               const float* __restrict__ xR,
                                               float* __restrict__ sums) {
  int blk = blockIdx.x;                 // 512 blocks: img(2) x c(64) x slice(4)
  int img = blk >> 8, c = (blk >> 2) & 63, s = blk & 3;
  const float* x = img ? xR : xL;
  float sm = 0.f, sq = 0.f;
  for (int n = 2*s; n < 2*s+2; ++n) {
    const float4* p = (const float4*)(x + ((size_t)(n*64+c))*HW);
    for (int i = threadIdx.x; i < 4096; i += 256) {
      float4 v = p[i];
      sm += (v.x+v.y)+(v.z+v.w);
      sq += (v.x*v.x+v.y*v.y)+(v.z*v.z+v.w*v.w);
    }
  }
  #pragma unroll
  for (int o = 32; o > 0; o >>= 1) { sm += __shfl_down(sm, o); sq += __shfl_down(sq, o); }
  __shared__ float rs[2][4];
  int wid = threadIdx.x >> 6;
  if ((threadIdx.x & 63) == 0) { rs[0][wid] = sm; rs[1][wid] = sq; }
  __syncthreads();
  if (threadIdx.x == 0) {
    sm = (rs[0][0]+rs[0][1])+(rs[0][2]+rs[0][3]);
    sq = (rs[1][0]+rs[1][1])+(rs[1][2]+rs[1][3]);
    atomicAdd(&sums[(img*64+c)*2+0], sm);
    atomicAdd(&sums[(img*64+c)*2+1], sq);
  }
}

__global__ __launch_bounds__(128) void k_finalize(const float* __restrict__ sums,
                                                  const float* __restrict__ gamma,
                                                  const float* __restrict__ beta,
                                                  float* __restrict__ ss) {
  int t = threadIdx.x;
  if (t < 128) {
    int c = t & 63;
    float sm = sums[t*2], sq = sums[t*2+1];
    float mean = sm * (1.f/131072.f);
    float var  = sq * (1.f/131072.f) - mean*mean;
    float scale = gamma[c] * rsqrtf(var + 1e-5f);
    ss[t*2+0] = scale;
    ss[t*2+1] = beta[c] - mean*scale;
  }
}

// ---------------- grouped 3x3 conv, pad=1, dual-image dispatch (z=16) --------
// MODE 0: y = lrelu(conv(BN(in)))               -> out = y1
// MODE 1: y2 = conv(in) + BN(xres); fused 1x1:  -> out = Q/K = qw*y2 + qb
//         plus per-(b,c,h) row sums via atomics (mean subtraction in pam)
// XCD-slice swizzle: all 64 tiles of one (g,nz) slice land on one XCD so halo
// cache lines (the neighbor tile's interior) hit that XCD's L2.
// LDS (floats), conflict-audited layouts:
//   in_t : ic*364 + ry*20 + (x_local+4); interior aligned ds_write/read_b128.
//   w_t  : WOFF + oc*200 + ic*12 + k     (200 mod 32 = 8 -> oc groups spread)
//   MODE1 reuse: y2_t oc*328 + py*20 + px ; qw_t WOFF+oc*16+ic ; qb_t QBOFF+oc
#define WOFF  5824
#define QBOFF (WOFF + 256)

template<int MODE>
__global__ __launch_bounds__(256, 4) void k_conv(
    const float* __restrict__ inL, const float* __restrict__ inR,
    const float* __restrict__ xresL, const float* __restrict__ xresR,
    const float* __restrict__ w, const float* __restrict__ bias,
    const float* __restrict__ ss,
    float* __restrict__ outL_, float* __restrict__ outR_,
    const float* __restrict__ qwL, const float* __restrict__ qbL,
    const float* __restrict__ qwR, const float* __restrict__ qbR,
    float* __restrict__ rsL, float* __restrict__ rsR) {
  __shared__ float smem[9024];
  // ---- bijective XCD-slice swizzle (gridDim.x=64, gridDim.y=4) ----
  int l = blockIdx.x + (blockIdx.y << 6) + (blockIdx.z << 8);
  int spx = (gridDim.y * gridDim.z) >> 3;    // slices per XCD
  int jj = l >> 3;
  int tile = jj & 63;
  int slice = (l & 7) * spx + (jj >> 6);
  int g = slice & 3;
  int nz = slice >> 2;

  int img = nz >> 3, n = nz & 7;
  const float* in   = img ? inR : inL;
  const float* xres = img ? xresR : xresL;
  const float* ssp  = ss + img*128;
  float* out        = img ? outR_ : outL_;
  const float* qw1  = img ? qwR : qwL;
  const float* qb1  = img ? qbR : qbL;
  float* rowsum     = img ? rsR : rsL;

  int x0 = (tile & 7) << 4, y0 = (tile >> 3) << 4;
  int t = threadIdx.x;
  int n64 = n*64 + g*16;

  // ---- stage 3x3 weights: thread t -> (oc = t>>4, ic = t&15), 9 taps ----
  {
    int ocw = t >> 4, icw = t & 15;
    const float* wp = w + (size_t)(g*16 + ocw)*144 + icw*9;
    float* wd = &smem[WOFF + ocw*200 + icw*12];
    #pragma unroll
    for (int k = 0; k < 9; ++k) wd[k] = wp[k];
  }

  // ---- stage interior 16x16 per channel: aligned ds_write_b128 ----
  {
    int q = t & 3, ry = ((t >> 2) & 15) + 1, icb = t >> 6;   // icb 0..3
    int gy = y0 + ry - 1;                                    // in [0,127]
    const float* rowp = in + ((size_t)(n64 + icb)*128 + gy)*128 + x0 + (q << 2);
    float* dst = &smem[icb*364 + ry*20 + 4 + (q << 2)];
    #pragma unroll
    for (int k = 0; k < 4; ++k) {                            // ic = icb + 4k
      float4 v4 = *(const float4*)(rowp + (size_t)(4*k)*HW);
      if (MODE == 0) {
        int cc = (g*16 + icb + 4*k) * 2;
        float sA = ssp[cc], sB = ssp[cc+1];
        v4.x = fmaf(v4.x,sA,sB); v4.y = fmaf(v4.y,sA,sB);
        v4.z = fmaf(v4.z,sA,sB); v4.w = fmaf(v4.w,sA,sB);
      }
      *(float4*)(dst + 4*k*364) = v4;
    }
  }
  // ---- stage halo: left/right columns (t<64), top/bottom rows (64<=t<192) ----
  if (t < 64) {
    int side = t >> 5, lane = t & 31;
    int ic = lane >> 1, half = lane & 1;
    int gx = side ? x0 + 16 : x0 - 1;
    bool xok = ((unsigned)gx < 128u);
    int gxc = xok ? gx : 0;
    int col = side ? 20 : 3;          // x_local 16 -> 20, x_local -1 -> 3
    const float* base = in + (size_t)(n64 + ic)*HW;
    float sA = 0.f, sB = 0.f;
    if (MODE == 0) { int cc = (g*16+ic)*2; sA = ssp[cc]; sB = ssp[cc+1]; }
    #pragma unroll
    for (int k = 0; k < 9; ++k) {
      int r = half*9 + k;
      int gy = y0 - 1 + r;
      bool ok = xok && ((unsigned)gy < 128u);
      int gyc = ((unsigned)gy < 128u) ? gy : 0;
      float v = base[(size_t)gyc*128 + gxc];
      if (MODE == 0) v = fmaf(v, sA, sB);
      smem[ic*364 + r*20 + col] = ok ? v : 0.f;
    }
  } else if (t < 192) {
    int j = t - 64;
    int half = j >> 6, l2 = j & 63;
    int ic = l2 >> 2, q = l2 & 3;
    int gy = half ? y0 + 16 : y0 - 1;
    bool ok = ((unsigned)gy < 128u);
    int gyc = ok ? gy : 0;
    float4 v4 = *(const float4*)&in[((size_t)(n64 + ic)*128 + gyc)*128 + x0 + (q << 2)];
    if (MODE == 0) {
      int cc = (g*16+ic)*2;
      float sA = ssp[cc], sB = ssp[cc+1];
      v4.x = fmaf(v4.x,sA,sB); v4.y = fmaf(v4.y,sA,sB);
      v4.z = fmaf(v4.z,sA,sB); v4.w = fmaf(v4.w,sA,sB);
    }
    if (!ok) { v4.x = 0.f; v4.y = 0.f; v4.z = 0.f; v4.w = 0.f; }
    int ry = half ? 17 : 0;
    *(float4*)&smem[ic*364 + ry*20 + 4 + (q << 2)] = v4;
  }
  __syncthreads();

  int oc = t >> 4, sub = t & 15;
  int sy = (sub >> 2) << 2, sx = (sub & 3) << 2;
  int c = g*16 + oc;
  float acc[4][4];
  float bv = bias[c];
  #pragma unroll
  for (int i = 0; i < 4; ++i)
    #pragma unroll
    for (int j = 0; j < 4; ++j) acc[i][j] = bv;

  for (int ic = 0; ic < 16; ++ic) {
    const float* it = &smem[ic*364 + sy*20 + sx];
    float win[6][6];
    #pragma unroll
    for (int r = 0; r < 6; ++r) {
      const float* rp = it + r*20;
      float lw = rp[3];                           // x_local sx-1
      const float4 m4 = *(const float4*)(rp + 4); // x_local sx..sx+3 (aligned)
      float rw = rp[8];                           // x_local sx+4
      win[r][0]=lw; win[r][1]=m4.x; win[r][2]=m4.y;
      win[r][3]=m4.z; win[r][4]=m4.w; win[r][5]=rw;
    }
    const float4 w0 = *(const float4*)&smem[WOFF + oc*200 + ic*12];
    const float4 w1 = *(const float4*)&smem[WOFF + oc*200 + ic*12 + 4];
    const float  w8 = smem[WOFF + oc*200 + ic*12 + 8];
    float wv[9] = {w0.x,w0.y,w0.z,w0.w,w1.x,w1.y,w1.z,w1.w,w8};
    #pragma unroll
    for (int i = 0; i < 4; ++i)
      #pragma unroll
      for (int j = 0; j < 4; ++j) {
        float a = acc[i][j];
        #pragma unroll
        for (int ky = 0; ky < 3; ++ky)
          #pragma unroll
          for (int kx = 0; kx < 3; ++kx)
            a = fmaf(win[i+ky][j+kx], wv[ky*3+kx], a);
        acc[i][j] = a;
      }
  }

  if (MODE == 0) {
    #pragma unroll
    for (int i = 0; i < 4; ++i) {
      int oy = y0 + sy + i;
      size_t rowbase = ((size_t)(n*64+c)*128 + oy)*128;
      float4 o;
      o.x = acc[i][0] > 0.f ? acc[i][0] : 0.1f*acc[i][0];
      o.y = acc[i][1] > 0.f ? acc[i][1] : 0.1f*acc[i][1];
      o.z = acc[i][2] > 0.f ? acc[i][2] : 0.1f*acc[i][2];
      o.w = acc[i][3] > 0.f ? acc[i][3] : 0.1f*acc[i][3];
      *(float4*)&out[rowbase + x0 + sx] = o;
    }
  } else {
    // y2 = conv + BN(xres), stash in LDS (in_t + w_t regions are dead now)
    float sA = ssp[c*2], sB = ssp[c*2+1];
    __syncthreads();   // all in_t/w_t reads complete before aliasing
    #pragma unroll
    for (int i = 0; i < 4; ++i) {
      int oy = y0 + sy + i;
      size_t rowbase = ((size_t)(n*64+c)*128 + oy)*128;
      const float4 xr4 = *(const float4*)&xres[rowbase + x0 + sx];
      float4 v4;
      v4.x = acc[i][0] + fmaf(xr4.x, sA, sB);
      v4.y = acc[i][1] + fmaf(xr4.y, sA, sB);
      v4.z = acc[i][2] + fmaf(xr4.z, sA, sB);
      v4.w = acc[i][3] + fmaf(xr4.w, sA, sB);
      *(float4*)&smem[oc*328 + (sy+i)*20 + sx] = v4;
    }
    smem[WOFF + t] = qw1[g*256 + t];
    if (t < 16) smem[QBOFF + t] = qb1[g*16 + t];
    __syncthreads();

    float qa[4][4];
    float bq = smem[QBOFF + oc];
    #pragma unroll
    for (int i = 0; i < 4; ++i)
      #pragma unroll
      for (int j = 0; j < 4; ++j) qa[i][j] = bq;
    #pragma unroll 4
    for (int ic = 0; ic < 16; ++ic) {
      float wq = smem[WOFF + oc*16 + ic];
      #pragma unroll
      for (int i = 0; i < 4; ++i) {
        const float4 yv = *(const float4*)&smem[ic*328 + (sy+i)*20 + sx];
        qa[i][0] = fmaf(wq, yv.x, qa[i][0]);
        qa[i][1] = fmaf(wq, yv.y, qa[i][1]);
        qa[i][2] = fmaf(wq, yv.z, qa[i][2]);
        qa[i][3] = fmaf(wq, yv.w, qa[i][3]);
      }
    }
    #pragma unroll
    for (int i = 0; i < 4; ++i) {
      int oy = y0 + sy + i;
      size_t rowbase = ((size_t)(n*64+c)*128 + oy)*128;
      float4 o4 = make_float4(qa[i][0], qa[i][1], qa[i][2], qa[i][3]);
      *(float4*)&out[rowbase + x0 + sx] = o4;
      float r = (qa[i][0]+qa[i][1]) + (qa[i][2]+qa[i][3]);
      r += __shfl_xor(r, 1);
      r += __shfl_xor(r, 2);
      if ((t & 3) == 0) atomicAdd(&rowsum[(size_t)(n*64+c)*128 + oy], r);
    }
  }
}

// ---------------- PAM core: one block per (b,h) row, ~78 KB LDS -> 2 blk/CU ----
// Q/K arrive WITHOUT mean subtraction; P1 subtracts rowsum/128 at stage time.
// K ALIASES outR (d_out right half): each block reads its K rows in P1 strictly
// before writing the same rows in P6 (barrier-ordered, per-block private).
// K/outR are therefore NOT __restrict__; P6's epilogue is hand-batched
// (all XR loads into registers, then all outR stores) so the conservative
// aliasing assumption costs nothing.
__device__ __forceinline__ int SW(int r, int c) {
  return (r << 7) + (((c >> 2) ^ (r & 31)) << 2) + (c & 3);
}
__device__ __forceinline__ int SWQ(int r, int q) {
  return (r << 7) + ((q ^ (r & 31)) << 2);
}

__global__ __launch_bounds__(512, 4) void k_pam(const float* __restrict__ Q,
                                                const float* K,
                                                const float* __restrict__ XL,
                                                const float* __restrict__ XR,
                                                float* __restrict__ outL,
                                                float* outR,
                                                const float* __restrict__ rsL,
                                                const float* __restrict__ rsR) {
  extern __shared__ float smp[];
  float* ST   = smp;            // 16384 floats, swizzled score -> M_rl
  float* CHB  = smp + 16384;    // 2048 floats: QK chunks / x chunks / scratch
  float* rmax = smp + 18432;
  float* rinv = rmax + 128;
  float* cmax = rmax + 256;
  float* cinv = rmax + 384;
  float* Vl   = rmax + 512;
  float* Vr   = rmax + 640;
  float* Pu   = rmax + 768;
  float* Qv   = rmax + 896;
  float* ms   = rmax + 1024;    // [0] = global max
  float* pm   = CHB;            // P2/P3 partial scratch overlaps chunk buffer
  float* pl   = CHB + 512;
  float* pm2  = CHB + 1024;
  float* pl2  = CHB + 1536;

  int t = threadIdx.x;
  int b = blockIdx.x >> 7, h = blockIdx.x & 127;
  size_t qbase = ((size_t)(b*64)*128 + h)*128;   // + c*HW + u

  // ---- P1: score -> ST (swizzled); chunk loads prefetched into registers ----
  {
    int u0 = (t & 31) << 2, v0 = (t >> 5) << 3;
    float a0[8], a1[8], a2[8], a3[8];
    #pragma unroll
    for (int j = 0; j < 8; ++j) { a0[j]=0.f; a1[j]=0.f; a2[j]=0.f; a3[j]=0.f; }
    int half = t >> 8;               // 0 = Q, 1 = K
    int cl_ld = (t >> 5) & 7;
    int u4_ld = (t & 31) << 2;
    const float* src = half ? K : Q;
    const float* rsum = half ? rsR : rsL;
    // prefetch chunk 0
    float mean = rsum[((size_t)b*64 + cl_ld)*128 + h] * (1.f/128.f);
    float4 v = *(const float4*)&src[qbase + (size_t)cl_ld*HW + u4_ld];
    for (int cb = 0; cb < 8; ++cb) {
      __syncthreads();   // previous chunk fully consumed
      v.x -= mean; v.y -= mean; v.z -= mean; v.w -= mean;
      *(float4*)&CHB[half*1024 + cl_ld*128 + u4_ld] = v;
      if (cb < 7) {      // issue next chunk's loads; latency hides under FMAs
        mean = rsum[((size_t)b*64 + (cb+1)*8 + cl_ld)*128 + h] * (1.f/128.f);
        v = *(const float4*)&src[qbase + (size_t)((cb+1)*8 + cl_ld)*HW + u4_ld];
      }
      __syncthreads();
      #pragma unroll
      for (int cl = 0; cl < 8; ++cl) {
        const float4 qv = *(const float4*)&CHB[cl*128 + u0];
        const float4 k0 = *(const float4*)&CHB[1024 + cl*128 + v0];
        const float4 k1 = *(const float4*)&CHB[1024 + cl*128 + v0 + 4];
        float kk[8] = {k0.x,k0.y,k0.z,k0.w,k1.x,k1.y,k1.z,k1.w};
        #pragma unroll
        for (int j = 0; j < 8; ++j) {
          float kv = kk[j];
          a0[j] = fmaf(qv.x, kv, a0[j]);
          a1[j] = fmaf(qv.y, kv, a1[j]);
          a2[j] = fmaf(qv.z, kv, a2[j]);
          a3[j] = fmaf(qv.w, kv, a3[j]);
        }
      }
    }
    #pragma unroll
    for (int j = 0; j < 8; ++j) {
      int r = v0 + j;
      *(float4*)&ST[SWQ(r, u0 >> 2)] = make_float4(a0[j], a1[j], a2[j], a3[j]);
    }
  }
  __syncthreads();

  // ---- P2: row stats (over v, fixed u) + col stats (over u, fixed v) ----
  {
    int u = t & 127, q = t >> 7, vb = q << 5;
    float m = -1e30f;
    for (int v = vb; v < vb+32; ++v) m = fmaxf(m, ST[SW(v, u)]);
    float l = 0.f;
    for (int v = vb; v < vb+32; ++v) l += __expf(ST[SW(v, u)] - m);
    float m2 = -1e30f;
    for (int k = (vb >> 2); k < (vb >> 2) + 8; ++k) {
      const float4 x4 = *(const float4*)&ST[SWQ(u, k)];
      m2 = fmaxf(m2, fmaxf(fmaxf(x4.x, x4.y), fmaxf(x4.z, x4.w)));
    }
    float l2 = 0.f;
    for (int k = (vb >> 2); k < (vb >> 2) + 8; ++k) {
      const float4 x4 = *(const float4*)&ST[SWQ(u, k)];
      l2 += (__expf(x4.x-m2)+__expf(x4.y-m2)) + (__expf(x4.z-m2)+__expf(x4.w-m2));
    }
    pm[t] = m; pl[t] = l;
    pm2[t] = m2; pl2[t] = l2;
  }
  __syncthreads();
  if (t < 256) {
    int u = t & 127;
    const float* PM = (t < 128) ? pm : pm2;
    const float* PL = (t < 128) ? pl : pl2;
    float m = fmaxf(fmaxf(PM[u], PM[128+u]), fmaxf(PM[256+u], PM[384+u]));
    float l = PL[u]*__expf(PM[u]-m) + PL[128+u]*__expf(PM[128+u]-m)
            + PL[256+u]*__expf(PM[256+u]-m) + PL[384+u]*__expf(PM[384+u]-m);
    if (t < 128) { rmax[u] = m; rinv[u] = 1.f/l; }
    else         { cmax[u] = m; cinv[u] = 1.f/l; }
  }
  __syncthreads();

  // ---- global max m* (one wave) ----
  if (t < 64) {
    float m = fmaxf(rmax[t], rmax[t+64]);
    #pragma unroll
    for (int o = 32; o > 0; o >>= 1) m = fmaxf(m, __shfl_down(m, o));
    if (t == 0) ms[0] = m;
  }
  __syncthreads();

  // ---- Pu/Qv + in-place transform ST -> M_rl ----
  {
    float ms0 = ms[0];
    if (t < 128)      Pu[t] = __expf(rmax[t] - ms0) / rinv[t];
    else if (t < 256) { int v = t - 128; Qv[v] = __expf(ms0 - cmax[v]) * cinv[v]; }
    int u = t & 127, q = t >> 7;
    float ru = rmax[u], ri = rinv[u];
    for (int v = (q << 5); v < (q << 5) + 32; ++v) {
      int a = SW(v, u);
      ST[a] = __expf(ST[a] - ru) * ri;
    }
  }
  __syncthreads();

  // ---- P3: V partials (exp-free) ----
  {
    int u = t & 127, q = t >> 7, vb = q << 5;
    int rcl[5]; float wL[5], qvd[5];
    #pragma unroll
    for (int d = 0; d < 5; ++d) {
      int uu = u - 2 + d;
      bool ok = (uu >= 0 && uu < 128);
      rcl[d] = ok ? uu : u;
      wL[d]  = ok ? 1.f : 0.f;
      qvd[d] = ok ? Qv[uu] : 0.f;
    }
    float pu_u = Pu[u];
    float accL = 0.f, accR = 0.f;
    // accL: row-direction reads (conflict-free), plain v order
    for (int v = vb; v < vb+32; ++v) {
      float rr0 = ST[SW(v, rcl[0])], rr1 = ST[SW(v, rcl[1])];
      float rr2 = ST[SW(v, u)];
      float rr3 = ST[SW(v, rcl[3])], rr4 = ST[SW(v, rcl[4])];
      float R = rr2 + (wL[0]*rr0 + wL[1]*rr1) + (wL[3]*rr3 + wL[4]*rr4);
      accL = fmaf(R * rr2, Qv[v], accL);
    }
    accL *= pu_u;
    // accR: column-direction reads; per-lane bank-spread v order
    {
      int ush = u >> 3;
      #pragma unroll 2
      for (int a = 0; a < 8; ++a) {
        #pragma unroll
        for (int bq = 0; bq < 4; ++bq) {
          int v = vb + (a << 2) + ((bq + ush) & 3);
          float cc0 = ST[SW(rcl[0], v)], cc1 = ST[SW(rcl[1], v)];
          float cc2 = ST[SW(u, v)];
          float cc3 = ST[SW(rcl[3], v)], cc4 = ST[SW(rcl[4], v)];
          float G = cc2*qvd[2] + (cc0*qvd[0] + cc1*qvd[1]) + (cc3*qvd[3] + cc4*qvd[4]);
          accR = fmaf(G * cc2, Pu[v], accR);
        }
      }
    }
    __syncthreads();   // P2 combine readers done before overwriting pm/pl
    pm[t] = accL; pl[t] = accR;
  }
  __syncthreads();
  if (t < 128) {
    float vsL = pm[t]+pm[128+t]+pm[256+t]+pm[384+t];
    float vsR = pl[t]+pl[128+t]+pl[256+t]+pl[384+t];
    Vl[t] = tanhf(5.f*vsL);
    Vr[t] = tanhf(5.f*vsR);
  }

  int ul = t & 63, c0 = (t >> 6) << 3;
  int c_ld = t >> 3, q_ld = (t & 7) << 2;     // chunk load: c 0..63, 4 v's
  int csw_st = c_ld ^ (((q_ld >> 2) & 7) << 3);   // swizzled staging column

  // ---- P5: out_left = xl*(1-Vl) + (M_rl @ xr)*Vl, xr in 8 KB v-chunks ----
  {
    float acc0[8], acc1[8];
    #pragma unroll
    for (int j = 0; j < 8; ++j) { acc0[j]=0.f; acc1[j]=0.f; }
    float4 r4 = *(const float4*)&XR[qbase + (size_t)c_ld*HW + q_ld];  // chunk 0
    for (int cb = 0; cb < 4; ++cb) {
      __syncthreads();   // prev chunk consumed (and Vl/Vr readers done)
      CHB[(q_ld+0)*64+csw_st] = r4.x; CHB[(q_ld+1)*64+csw_st] = r4.y;
      CHB[(q_ld+2)*64+csw_st] = r4.z; CHB[(q_ld+3)*64+csw_st] = r4.w;
      if (cb < 3)
        r4 = *(const float4*)&XR[qbase + (size_t)c_ld*HW + ((cb+1) << 5) + q_ld];
      __syncthreads();
      int vb = cb << 5;
      for (int vv = 0; vv < 32; ++vv) {
        int v = vb + vv;
        float m0 = ST[SW(v, ul)];
        float m1 = ST[SW(v, ul+64)];
        int cs = c0 ^ (((vv >> 2) & 7) << 3);
        const float4 xa = *(const float4*)&CHB[vv*64 + cs];
        const float4 xb = *(const float4*)&CHB[vv*64 + cs + 4];
        acc0[0]=fmaf(m0,xa.x,acc0[0]); acc0[1]=fmaf(m0,xa.y,acc0[1]);
        acc0[2]=fmaf(m0,xa.z,acc0[2]); acc0[3]=fmaf(m0,xa.w,acc0[3]);
        acc0[4]=fmaf(m0,xb.x,acc0[4]); acc0[5]=fmaf(m0,xb.y,acc0[5]);
        acc0[6]=fmaf(m0,xb.z,acc0[6]); acc0[7]=fmaf(m0,xb.w,acc0[7]);
        acc1[0]=fmaf(m1,xa.x,acc1[0]); acc1[1]=fmaf(m1,xa.y,acc1[1]);
        acc1[2]=fmaf(m1,xa.z,acc1[2]); acc1[3]=fmaf(m1,xa.w,acc1[3]);
        acc1[4]=fmaf(m1,xb.x,acc1[4]); acc1[5]=fmaf(m1,xb.y,acc1[5]);
        acc1[6]=fmaf(m1,xb.z,acc1[6]); acc1[7]=fmaf(m1,xb.w,acc1[7]);
      }
    }
    float vl0 = Vl[ul], vl1 = Vl[ul+64];
    #pragma unroll
    for (int j = 0; j < 8; ++j) {
      size_t o0 = qbase + (size_t)(c0+j)*HW + ul;
      outL[o0]    = XL[o0]   *(1.f-vl0) + acc0[j]*vl0;
      outL[o0+64] = XL[o0+64]*(1.f-vl1) + acc1[j]*vl1;
    }
  }

  // ---- P6: out_right = xr*(1-Vr) + (M_lr @ xl)*Vr, xl in 8 KB v-chunks ----
  // M_lr[u,v] = ST[SW(u,v)] * Pu[v] * Qv[u]
  {
    float acc0[8], acc1[8];
    #pragma unroll
    for (int j = 0; j < 8; ++j) { acc0[j]=0.f; acc1[j]=0.f; }
    float qv_u0 = Qv[ul], qv_u1 = Qv[ul+64];
    float4 r4 = *(const float4*)&XL[qbase + (size_t)c_ld*HW + q_ld];  // chunk 0
    for (int cb = 0; cb < 4; ++cb) {
      __syncthreads();
      CHB[(q_ld+0)*64+csw_st] = r4.x; CHB[(q_ld+1)*64+csw_st] = r4.y;
      CHB[(q_ld+2)*64+csw_st] = r4.z; CHB[(q_ld+3)*64+csw_st] = r4.w;
      if (cb < 3)
        r4 = *(const float4*)&XL[qbase + (size_t)c_ld*HW + ((cb+1) << 5) + q_ld];
      __syncthreads();
      int qb = cb << 3;
      for (int lq = 0; lq < 8; ++lq) {
        const float4 s0 = *(const float4*)&ST[SWQ(ul,    qb+lq)];
        const float4 s1 = *(const float4*)&ST[SWQ(ul+64, qb+lq)];
        const float4 pu4 = *(const float4*)&Pu[(qb+lq) << 2];
        float sv0[4] = {s0.x, s0.y, s0.z, s0.w};
        float sv1[4] = {s1.x, s1.y, s1.z, s1.w};
        float pv[4]  = {pu4.x, pu4.y, pu4.z, pu4.w};
        int cs = c0 ^ ((lq & 7) << 3);
        #pragma unroll
        for (int k = 0; k < 4; ++k) {
          float m0 = sv0[k] * pv[k] * qv_u0;
          float m1 = sv1[k] * pv[k] * qv_u1;
          const float4 xa0 = *(const float4*)&CHB[((lq<<2)+k)*64 + cs];
          const float4 xb0 = *(const float4*)&CHB[((lq<<2)+k)*64 + cs + 4];
          acc0[0]=fmaf(m0,xa0.x,acc0[0]); acc0[1]=fmaf(m0,xa0.y,acc0[1]);
          acc0[2]=fmaf(m0,xa0.z,acc0[2]); acc0[3]=fmaf(m0,xa0.w,acc0[3]);
          acc0[4]=fmaf(m0,xb0.x,acc0[4]); acc0[5]=fmaf(m0,xb0.y,acc0[5]);
          acc0[6]=fmaf(m0,xb0.z,acc0[6]); acc0[7]=fmaf(m0,xb0.w,acc0[7]);
          acc1[0]=fmaf(m1,xa0.x,acc1[0]); acc1[1]=fmaf(m1,xa0.y,acc1[1]);
          acc1[2]=fmaf(m1,xa0.z,acc1[2]); acc1[3]=fmaf(m1,xa0.w,acc1[3]);
          acc1[4]=fmaf(m1,xb0.x,acc1[4]); acc1[5]=fmaf(m1,xb0.y,acc1[5]);
          acc1[6]=fmaf(m1,xb0.z,acc1[6]); acc1[7]=fmaf(m1,xb0.w,acc1[7]);
        }
      }
    }
    float vr0 = Vr[ul], vr1 = Vr[ul+64];
    // hand-batched epilogue: all XR loads first, then all outR stores
    // (K aliases outR; explicit ordering removes any aliasing serialization)
    float xr0[8], xr1[8];
    #pragma unroll
    for (int j = 0; j < 8; ++j) {
      size_t o0 = qbase + (size_t)(c0+j)*HW + ul;
      xr0[j] = XR[o0];
      xr1[j] = XR[o0+64];
    }
    #pragma unroll
    for (int j = 0; j < 8; ++j) {
      size_t o0 = qbase + (size_t)(c0+j)*HW + ul;
      outR[o0]    = xr0[j]*(1.f-vr0) + acc0[j]*vr0;
      outR[o0+64] = xr1[j]*(1.f-vr1) + acc1[j]*vr1;
    }
  }
}

extern "C" void kernel_launch(void* const* d_in, const int* in_sizes, int n_in,
                              void* d_out, int out_size, void* d_ws, size_t ws_size,
                              hipStream_t stream) {
  const float* xL    = (const float*)d_in[0];
  const float* xR    = (const float*)d_in[1];
  const float* gamma = (const float*)d_in[2];
  const float* beta  = (const float*)d_in[3];
  const float* rw1   = (const float*)d_in[4];
  const float* rb1   = (const float*)d_in[5];
  const float* rw2   = (const float*)d_in[6];
  const float* rb2   = (const float*)d_in[7];
  const float* qw    = (const float*)d_in[8];
  const float* qb    = (const float*)d_in[9];
  const float* kw    = (const float*)d_in[10];
  const float* kb    = (const float*)d_in[11];
  float* out = (float*)d_out;
  char* ws = (char*)d_ws;

  const size_t BUF = (size_t)BB*CH_N*HW*4;   // 33,554,432 bytes
  float* y1L  = (float*)(ws);                // B0
  float* y1R  = (float*)(ws + BUF);          // B1
  float* Qb   = (float*)(ws + 2*BUF);        // B2: Q
  float* sums = (float*)(ws + 3*BUF);        // 256 floats
  float* ss   = sums + 256;                  // 256 floats
  float* rsL  = sums + 512;                  // 8*64*128 floats
  float* rsR  = rsL + (size_t)BB*CH_N*HH;

  // K lives in d_out's right half (= outR). Safe: pam block (b,h) reads its
  // K rows in P1 strictly before writing the same rows in P6.
  float* Kb = out + (size_t)BB*CH_N*HW;

  hipMemsetAsync(sums, 0, (512 + 2*(size_t)BB*CH_N*HH)*sizeof(float), stream);
  k_stats<<<512, 256, 0, stream>>>(xL, xR, sums);
  k_finalize<<<1, 128, 0, stream>>>(sums, gamma, beta, ss);

  dim3 cg(64, 4, 16);
  k_conv<0><<<cg, 256, 0, stream>>>(xL, xR, xL, xR, rw1, rb1, ss, y1L, y1R,
                                    nullptr, nullptr, nullptr, nullptr, nullptr, nullptr);
  k_conv<1><<<cg, 256, 0, stream>>>(y1L, y1R, xL, xR, rw2, rb2, ss, Qb, Kb,
                                    qw, qb, kw, kb, rsL, rsR);

  const int SMEM = 19464 * 4;   // 77,856 B -> 2 blocks/CU
  hipFuncSetAttribute((const void*)k_pam, hipFuncAttributeMaxDynamicSharedMemorySize, SMEM);
  k_pam<<<1024, 512, SMEM, stream>>>(Qb, Kb, xL, xR, out, Kb, rsL, rsR);
}

// Round 8
// 457.989 us; speedup vs baseline: 1.0654x; 1.0582x over previous
//
#include <hip/hip_runtime.h>

#define CH_N 64
#define HH 128
#define WW 128
#define BB 8
#define HW (HH*WW)

// ---------------- BN stats: per-channel partial sums (atomics) ----------------
__global__ __launch_bounds__(256) void k_stats(const float* __restrict__ xL,
                                               const float* __restrict__ xR,
                                               float* __restrict__ sums) {
  int blk = blockIdx.x;                 // 512 blocks: img(2) x c(64) x slice(4)
  int img = blk >> 8, c = (blk >> 2) & 63, s = blk & 3;
  const float* x = img ? xR : xL;
  float sm = 0.f, sq = 0.f;
  for (int n = 2*s; n < 2*s+2; ++n) {
    const float4* p = (const float4*)(x + ((size_t)(n*64+c))*HW);
    for (int i = threadIdx.x; i < 4096; i += 256) {
      float4 v = p[i];
      sm += (v.x+v.y)+(v.z+v.w);
      sq += (v.x*v.x+v.y*v.y)+(v.z*v.z+v.w*v.w);
    }
  }
  #pragma unroll
  for (int o = 32; o > 0; o >>= 1) { sm += __shfl_down(sm, o); sq += __shfl_down(sq, o); }
  __shared__ float rs[2][4];
  int wid = threadIdx.x >> 6;
  if ((threadIdx.x & 63) == 0) { rs[0][wid] = sm; rs[1][wid] = sq; }
  __syncthreads();
  if (threadIdx.x == 0) {
    sm = (rs[0][0]+rs[0][1])+(rs[0][2]+rs[0][3]);
    sq = (rs[1][0]+rs[1][1])+(rs[1][2]+rs[1][3]);
    atomicAdd(&sums[(img*64+c)*2+0], sm);
    atomicAdd(&sums[(img*64+c)*2+1], sq);
  }
}

__global__ __launch_bounds__(128) void k_finalize(const float* __restrict__ sums,
                                                  const float* __restrict__ gamma,
                                                  const float* __restrict__ beta,
                                                  float* __restrict__ ss) {
  int t = threadIdx.x;
  if (t < 128) {
    int c = t & 63;
    float sm = sums[t*2], sq = sums[t*2+1];
    float mean = sm * (1.f/131072.f);
    float var  = sq * (1.f/131072.f) - mean*mean;
    float scale = gamma[c] * rsqrtf(var + 1e-5f);
    ss[t*2+0] = scale;
    ss[t*2+1] = beta[c] - mean*scale;
  }
}

// ---------------- grouped 3x3 conv, pad=1, dual-image dispatch (z=16) --------
// MODE 0: y = lrelu(conv(BN(in)))               -> out = y1
// MODE 1: y2 = conv(in) + BN(xres); fused 1x1:  -> out = Q/K = qw*y2 + qb
//         plus per-(b,c,h) row sums via atomics (mean subtraction in pam)
// NOTE: XCD-slice swizzle tried in R6/R7 cost ~40 us (conv set is L3-resident;
// swizzle only broke conv<0>-write -> conv<1>-read dispatch-order L2 locality).
// Natural blockIdx mapping restored.
// LDS (floats), conflict-audited layouts:
//   in_t : ic*364 + ry*20 + (x_local+4); interior aligned ds_write/read_b128.
//   w_t  : WOFF + oc*200 + ic*12 + k     (200 mod 32 = 8 -> oc groups spread)
//   MODE1 reuse: y2_t oc*328 + py*20 + px ; qw_t WOFF+oc*16+ic ; qb_t QBOFF+oc
#define WOFF  5824
#define QBOFF (WOFF + 256)

template<int MODE>
__global__ __launch_bounds__(256, 4) void k_conv(
    const float* __restrict__ inL, const float* __restrict__ inR,
    const float* __restrict__ xresL, const float* __restrict__ xresR,
    const float* __restrict__ w, const float* __restrict__ bias,
    const float* __restrict__ ss,
    float* __restrict__ outL_, float* __restrict__ outR_,
    const float* __restrict__ qwL, const float* __restrict__ qbL,
    const float* __restrict__ qwR, const float* __restrict__ qbR,
    float* __restrict__ rsL, float* __restrict__ rsR) {
  __shared__ float smem[9024];
  int tile = blockIdx.x, g = blockIdx.y, nz = blockIdx.z;

  int img = nz >> 3, n = nz & 7;
  const float* in   = img ? inR : inL;
  const float* xres = img ? xresR : xresL;
  const float* ssp  = ss + img*128;
  float* out        = img ? outR_ : outL_;
  const float* qw1  = img ? qwR : qwL;
  const float* qb1  = img ? qbR : qbL;
  float* rowsum     = img ? rsR : rsL;

  int x0 = (tile & 7) << 4, y0 = (tile >> 3) << 4;
  int t = threadIdx.x;
  int n64 = n*64 + g*16;

  // ---- stage 3x3 weights: thread t -> (oc = t>>4, ic = t&15), 9 taps ----
  {
    int ocw = t >> 4, icw = t & 15;
    const float* wp = w + (size_t)(g*16 + ocw)*144 + icw*9;
    float* wd = &smem[WOFF + ocw*200 + icw*12];
    #pragma unroll
    for (int k = 0; k < 9; ++k) wd[k] = wp[k];
  }

  // ---- stage interior 16x16 per channel: aligned ds_write_b128 ----
  {
    int q = t & 3, ry = ((t >> 2) & 15) + 1, icb = t >> 6;   // icb 0..3
    int gy = y0 + ry - 1;                                    // in [0,127]
    const float* rowp = in + ((size_t)(n64 + icb)*128 + gy)*128 + x0 + (q << 2);
    float* dst = &smem[icb*364 + ry*20 + 4 + (q << 2)];
    #pragma unroll
    for (int k = 0; k < 4; ++k) {                            // ic = icb + 4k
      float4 v4 = *(const float4*)(rowp + (size_t)(4*k)*HW);
      if (MODE == 0) {
        int cc = (g*16 + icb + 4*k) * 2;
        float sA = ssp[cc], sB = ssp[cc+1];
        v4.x = fmaf(v4.x,sA,sB); v4.y = fmaf(v4.y,sA,sB);
        v4.z = fmaf(v4.z,sA,sB); v4.w = fmaf(v4.w,sA,sB);
      }
      *(float4*)(dst + 4*k*364) = v4;
    }
  }
  // ---- stage halo: left/right columns (t<64), top/bottom rows (64<=t<192) ----
  if (t < 64) {
    int side = t >> 5, lane = t & 31;
    int ic = lane >> 1, half = lane & 1;
    int gx = side ? x0 + 16 : x0 - 1;
    bool xok = ((unsigned)gx < 128u);
    int gxc = xok ? gx : 0;
    int col = side ? 20 : 3;          // x_local 16 -> 20, x_local -1 -> 3
    const float* base = in + (size_t)(n64 + ic)*HW;
    float sA = 0.f, sB = 0.f;
    if (MODE == 0) { int cc = (g*16+ic)*2; sA = ssp[cc]; sB = ssp[cc+1]; }
    #pragma unroll
    for (int k = 0; k < 9; ++k) {
      int r = half*9 + k;
      int gy = y0 - 1 + r;
      bool ok = xok && ((unsigned)gy < 128u);
      int gyc = ((unsigned)gy < 128u) ? gy : 0;
      float v = base[(size_t)gyc*128 + gxc];
      if (MODE == 0) v = fmaf(v, sA, sB);
      smem[ic*364 + r*20 + col] = ok ? v : 0.f;
    }
  } else if (t < 192) {
    int j = t - 64;
    int half = j >> 6, l2 = j & 63;
    int ic = l2 >> 2, q = l2 & 3;
    int gy = half ? y0 + 16 : y0 - 1;
    bool ok = ((unsigned)gy < 128u);
    int gyc = ok ? gy : 0;
    float4 v4 = *(const float4*)&in[((size_t)(n64 + ic)*128 + gyc)*128 + x0 + (q << 2)];
    if (MODE == 0) {
      int cc = (g*16+ic)*2;
      float sA = ssp[cc], sB = ssp[cc+1];
      v4.x = fmaf(v4.x,sA,sB); v4.y = fmaf(v4.y,sA,sB);
      v4.z = fmaf(v4.z,sA,sB); v4.w = fmaf(v4.w,sA,sB);
    }
    if (!ok) { v4.x = 0.f; v4.y = 0.f; v4.z = 0.f; v4.w = 0.f; }
    int ry = half ? 17 : 0;
    *(float4*)&smem[ic*364 + ry*20 + 4 + (q << 2)] = v4;
  }
  __syncthreads();

  int oc = t >> 4, sub = t & 15;
  int sy = (sub >> 2) << 2, sx = (sub & 3) << 2;
  int c = g*16 + oc;
  float acc[4][4];
  float bv = bias[c];
  #pragma unroll
  for (int i = 0; i < 4; ++i)
    #pragma unroll
    for (int j = 0; j < 4; ++j) acc[i][j] = bv;

  for (int ic = 0; ic < 16; ++ic) {
    const float* it = &smem[ic*364 + sy*20 + sx];
    float win[6][6];
    #pragma unroll
    for (int r = 0; r < 6; ++r) {
      const float* rp = it + r*20;
      float lw = rp[3];                           // x_local sx-1
      const float4 m4 = *(const float4*)(rp + 4); // x_local sx..sx+3 (aligned)
      float rw = rp[8];                           // x_local sx+4
      win[r][0]=lw; win[r][1]=m4.x; win[r][2]=m4.y;
      win[r][3]=m4.z; win[r][4]=m4.w; win[r][5]=rw;
    }
    const float4 w0 = *(const float4*)&smem[WOFF + oc*200 + ic*12];
    const float4 w1 = *(const float4*)&smem[WOFF + oc*200 + ic*12 + 4];
    const float  w8 = smem[WOFF + oc*200 + ic*12 + 8];
    float wv[9] = {w0.x,w0.y,w0.z,w0.w,w1.x,w1.y,w1.z,w1.w,w8};
    #pragma unroll
    for (int i = 0; i < 4; ++i)
      #pragma unroll
      for (int j = 0; j < 4; ++j) {
        float a = acc[i][j];
        #pragma unroll
        for (int ky = 0; ky < 3; ++ky)
          #pragma unroll
          for (int kx = 0; kx < 3; ++kx)
            a = fmaf(win[i+ky][j+kx], wv[ky*3+kx], a);
        acc[i][j] = a;
      }
  }

  if (MODE == 0) {
    #pragma unroll
    for (int i = 0; i < 4; ++i) {
      int oy = y0 + sy + i;
      size_t rowbase = ((size_t)(n*64+c)*128 + oy)*128;
      float4 o;
      o.x = acc[i][0] > 0.f ? acc[i][0] : 0.1f*acc[i][0];
      o.y = acc[i][1] > 0.f ? acc[i][1] : 0.1f*acc[i][1];
      o.z = acc[i][2] > 0.f ? acc[i][2] : 0.1f*acc[i][2];
      o.w = acc[i][3] > 0.f ? acc[i][3] : 0.1f*acc[i][3];
      *(float4*)&out[rowbase + x0 + sx] = o;
    }
  } else {
    // y2 = conv + BN(xres), stash in LDS (in_t + w_t regions are dead now)
    float sA = ssp[c*2], sB = ssp[c*2+1];
    __syncthreads();   // all in_t/w_t reads complete before aliasing
    #pragma unroll
    for (int i = 0; i < 4; ++i) {
      int oy = y0 + sy + i;
      size_t rowbase = ((size_t)(n*64+c)*128 + oy)*128;
      const float4 xr4 = *(const float4*)&xres[rowbase + x0 + sx];
      float4 v4;
      v4.x = acc[i][0] + fmaf(xr4.x, sA, sB);
      v4.y = acc[i][1] + fmaf(xr4.y, sA, sB);
      v4.z = acc[i][2] + fmaf(xr4.z, sA, sB);
      v4.w = acc[i][3] + fmaf(xr4.w, sA, sB);
      *(float4*)&smem[oc*328 + (sy+i)*20 + sx] = v4;
    }
    smem[WOFF + t] = qw1[g*256 + t];
    if (t < 16) smem[QBOFF + t] = qb1[g*16 + t];
    __syncthreads();

    float qa[4][4];
    float bq = smem[QBOFF + oc];
    #pragma unroll
    for (int i = 0; i < 4; ++i)
      #pragma unroll
      for (int j = 0; j < 4; ++j) qa[i][j] = bq;
    #pragma unroll 4
    for (int ic = 0; ic < 16; ++ic) {
      float wq = smem[WOFF + oc*16 + ic];
      #pragma unroll
      for (int i = 0; i < 4; ++i) {
        const float4 yv = *(const float4*)&smem[ic*328 + (sy+i)*20 + sx];
        qa[i][0] = fmaf(wq, yv.x, qa[i][0]);
        qa[i][1] = fmaf(wq, yv.y, qa[i][1]);
        qa[i][2] = fmaf(wq, yv.z, qa[i][2]);
        qa[i][3] = fmaf(wq, yv.w, qa[i][3]);
      }
    }
    #pragma unroll
    for (int i = 0; i < 4; ++i) {
      int oy = y0 + sy + i;
      size_t rowbase = ((size_t)(n*64+c)*128 + oy)*128;
      float4 o4 = make_float4(qa[i][0], qa[i][1], qa[i][2], qa[i][3]);
      *(float4*)&out[rowbase + x0 + sx] = o4;
      float r = (qa[i][0]+qa[i][1]) + (qa[i][2]+qa[i][3]);
      r += __shfl_xor(r, 1);
      r += __shfl_xor(r, 2);
      if ((t & 3) == 0) atomicAdd(&rowsum[(size_t)(n*64+c)*128 + oy], r);
    }
  }
}

// ---------------- PAM core: one block per (b,h) row, ~78 KB LDS -> 2 blk/CU ----
// Q/K arrive WITHOUT mean subtraction; P1 subtracts rowsum/128 at stage time.
// K ALIASES outR (d_out right half): each block reads its K rows in P1 strictly
// before writing the same rows in P6 (barrier-ordered, per-block private).
// K/outR are therefore NOT __restrict__; P6's epilogue is hand-batched
// (all XR loads into registers, then all outR stores) so the conservative
// aliasing assumption costs nothing.
__device__ __forceinline__ int SW(int r, int c) {
  return (r << 7) + (((c >> 2) ^ (r & 31)) << 2) + (c & 3);
}
__device__ __forceinline__ int SWQ(int r, int q) {
  return (r << 7) + ((q ^ (r & 31)) << 2);
}

__global__ __launch_bounds__(512, 4) void k_pam(const float* __restrict__ Q,
                                                const float* K,
                                                const float* __restrict__ XL,
                                                const float* __restrict__ XR,
                                                float* __restrict__ outL,
                                                float* outR,
                                                const float* __restrict__ rsL,
                                                const float* __restrict__ rsR) {
  extern __shared__ float smp[];
  float* ST   = smp;            // 16384 floats, swizzled score -> M_rl
  float* CHB  = smp + 16384;    // 2048 floats: QK chunks / x chunks / scratch
  float* rmax = smp + 18432;
  float* rinv = rmax + 128;
  float* cmax = rmax + 256;
  float* cinv = rmax + 384;
  float* Vl   = rmax + 512;
  float* Vr   = rmax + 640;
  float* Pu   = rmax + 768;
  float* Qv   = rmax + 896;
  float* ms   = rmax + 1024;    // [0] = global max
  float* pm   = CHB;            // P2/P3 partial scratch overlaps chunk buffer
  float* pl   = CHB + 512;
  float* pm2  = CHB + 1024;
  float* pl2  = CHB + 1536;

  int t = threadIdx.x;
  int b = blockIdx.x >> 7, h = blockIdx.x & 127;
  size_t qbase = ((size_t)(b*64)*128 + h)*128;   // + c*HW + u

  // ---- P1: score -> ST (swizzled); chunk loads prefetched into registers ----
  {
    int u0 = (t & 31) << 2, v0 = (t >> 5) << 3;
    float a0[8], a1[8], a2[8], a3[8];
    #pragma unroll
    for (int j = 0; j < 8; ++j) { a0[j]=0.f; a1[j]=0.f; a2[j]=0.f; a3[j]=0.f; }
    int half = t >> 8;               // 0 = Q, 1 = K
    int cl_ld = (t >> 5) & 7;
    int u4_ld = (t & 31) << 2;
    const float* src = half ? K : Q;
    const float* rsum = half ? rsR : rsL;
    // prefetch chunk 0
    float mean = rsum[((size_t)b*64 + cl_ld)*128 + h] * (1.f/128.f);
    float4 v = *(const float4*)&src[qbase + (size_t)cl_ld*HW + u4_ld];
    for (int cb = 0; cb < 8; ++cb) {
      __syncthreads();   // previous chunk fully consumed
      v.x -= mean; v.y -= mean; v.z -= mean; v.w -= mean;
      *(float4*)&CHB[half*1024 + cl_ld*128 + u4_ld] = v;
      if (cb < 7) {      // issue next chunk's loads; latency hides under FMAs
        mean = rsum[((size_t)b*64 + (cb+1)*8 + cl_ld)*128 + h] * (1.f/128.f);
        v = *(const float4*)&src[qbase + (size_t)((cb+1)*8 + cl_ld)*HW + u4_ld];
      }
      __syncthreads();
      #pragma unroll
      for (int cl = 0; cl < 8; ++cl) {
        const float4 qv = *(const float4*)&CHB[cl*128 + u0];
        const float4 k0 = *(const float4*)&CHB[1024 + cl*128 + v0];
        const float4 k1 = *(const float4*)&CHB[1024 + cl*128 + v0 + 4];
        float kk[8] = {k0.x,k0.y,k0.z,k0.w,k1.x,k1.y,k1.z,k1.w};
        #pragma unroll
        for (int j = 0; j < 8; ++j) {
          float kv = kk[j];
          a0[j] = fmaf(qv.x, kv, a0[j]);
          a1[j] = fmaf(qv.y, kv, a1[j]);
          a2[j] = fmaf(qv.z, kv, a2[j]);
          a3[j] = fmaf(qv.w, kv, a3[j]);
        }
      }
    }
    #pragma unroll
    for (int j = 0; j < 8; ++j) {
      int r = v0 + j;
      *(float4*)&ST[SWQ(r, u0 >> 2)] = make_float4(a0[j], a1[j], a2[j], a3[j]);
    }
  }
  __syncthreads();

  // ---- P2: row stats (over v, fixed u) + col stats (over u, fixed v) ----
  {
    int u = t & 127, q = t >> 7, vb = q << 5;
    float m = -1e30f;
    for (int v = vb; v < vb+32; ++v) m = fmaxf(m, ST[SW(v, u)]);
    float l = 0.f;
    for (int v = vb; v < vb+32; ++v) l += __expf(ST[SW(v, u)] - m);
    float m2 = -1e30f;
    for (int k = (vb >> 2); k < (vb >> 2) + 8; ++k) {
      const float4 x4 = *(const float4*)&ST[SWQ(u, k)];
      m2 = fmaxf(m2, fmaxf(fmaxf(x4.x, x4.y), fmaxf(x4.z, x4.w)));
    }
    float l2 = 0.f;
    for (int k = (vb >> 2); k < (vb >> 2) + 8; ++k) {
      const float4 x4 = *(const float4*)&ST[SWQ(u, k)];
      l2 += (__expf(x4.x-m2)+__expf(x4.y-m2)) + (__expf(x4.z-m2)+__expf(x4.w-m2));
    }
    pm[t] = m; pl[t] = l;
    pm2[t] = m2; pl2[t] = l2;
  }
  __syncthreads();
  if (t < 256) {
    int u = t & 127;
    const float* PM = (t < 128) ? pm : pm2;
    const float* PL = (t < 128) ? pl : pl2;
    float m = fmaxf(fmaxf(PM[u], PM[128+u]), fmaxf(PM[256+u], PM[384+u]));
    float l = PL[u]*__expf(PM[u]-m) + PL[128+u]*__expf(PM[128+u]-m)
            + PL[256+u]*__expf(PM[256+u]-m) + PL[384+u]*__expf(PM[384+u]-m);
    if (t < 128) { rmax[u] = m; rinv[u] = 1.f/l; }
    else         { cmax[u] = m; cinv[u] = 1.f/l; }
  }
  __syncthreads();

  // ---- global max m* (one wave) ----
  if (t < 64) {
    float m = fmaxf(rmax[t], rmax[t+64]);
    #pragma unroll
    for (int o = 32; o > 0; o >>= 1) m = fmaxf(m, __shfl_down(m, o));
    if (t == 0) ms[0] = m;
  }
  __syncthreads();

  // ---- Pu/Qv + in-place transform ST -> M_rl ----
  {
    float ms0 = ms[0];
    if (t < 128)      Pu[t] = __expf(rmax[t] - ms0) / rinv[t];
    else if (t < 256) { int v = t - 128; Qv[v] = __expf(ms0 - cmax[v]) * cinv[v]; }
    int u = t & 127, q = t >> 7;
    float ru = rmax[u], ri = rinv[u];
    for (int v = (q << 5); v < (q << 5) + 32; ++v) {
      int a = SW(v, u);
      ST[a] = __expf(ST[a] - ru) * ri;
    }
  }
  __syncthreads();

  // ---- P3: V partials (exp-free) ----
  {
    int u = t & 127, q = t >> 7, vb = q << 5;
    int rcl[5]; float wL[5], qvd[5];
    #pragma unroll
    for (int d = 0; d < 5; ++d) {
      int uu = u - 2 + d;
      bool ok = (uu >= 0 && uu < 128);
      rcl[d] = ok ? uu : u;
      wL[d]  = ok ? 1.f : 0.f;
      qvd[d] = ok ? Qv[uu] : 0.f;
    }
    float pu_u = Pu[u];
    float accL = 0.f, accR = 0.f;
    // accL: row-direction reads (conflict-free), plain v order
    for (int v = vb; v < vb+32; ++v) {
      float rr0 = ST[SW(v, rcl[0])], rr1 = ST[SW(v, rcl[1])];
      float rr2 = ST[SW(v, u)];
      float rr3 = ST[SW(v, rcl[3])], rr4 = ST[SW(v, rcl[4])];
      float R = rr2 + (wL[0]*rr0 + wL[1]*rr1) + (wL[3]*rr3 + wL[4]*rr4);
      accL = fmaf(R * rr2, Qv[v], accL);
    }
    accL *= pu_u;
    // accR: column-direction reads; per-lane bank-spread v order
    {
      int ush = u >> 3;
      #pragma unroll 2
      for (int a = 0; a < 8; ++a) {
        #pragma unroll
        for (int bq = 0; bq < 4; ++bq) {
          int v = vb + (a << 2) + ((bq + ush) & 3);
          float cc0 = ST[SW(rcl[0], v)], cc1 = ST[SW(rcl[1], v)];
          float cc2 = ST[SW(u, v)];
          float cc3 = ST[SW(rcl[3], v)], cc4 = ST[SW(rcl[4], v)];
          float G = cc2*qvd[2] + (cc0*qvd[0] + cc1*qvd[1]) + (cc3*qvd[3] + cc4*qvd[4]);
          accR = fmaf(G * cc2, Pu[v], accR);
        }
      }
    }
    __syncthreads();   // P2 combine readers done before overwriting pm/pl
    pm[t] = accL; pl[t] = accR;
  }
  __syncthreads();
  if (t < 128) {
    float vsL = pm[t]+pm[128+t]+pm[256+t]+pm[384+t];
    float vsR = pl[t]+pl[128+t]+pl[256+t]+pl[384+t];
    Vl[t] = tanhf(5.f*vsL);
    Vr[t] = tanhf(5.f*vsR);
  }

  int ul = t & 63, c0 = (t >> 6) << 3;
  int c_ld = t >> 3, q_ld = (t & 7) << 2;     // chunk load: c 0..63, 4 v's
  int csw_st = c_ld ^ (((q_ld >> 2) & 7) << 3);   // swizzled staging column

  // ---- P5: out_left = xl*(1-Vl) + (M_rl @ xr)*Vl, xr in 8 KB v-chunks ----
  {
    float acc0[8], acc1[8];
    #pragma unroll
    for (int j = 0; j < 8; ++j) { acc0[j]=0.f; acc1[j]=0.f; }
    float4 r4 = *(const float4*)&XR[qbase + (size_t)c_ld*HW + q_ld];  // chunk 0
    for (int cb = 0; cb < 4; ++cb) {
      __syncthreads();   // prev chunk consumed (and Vl/Vr readers done)
      CHB[(q_ld+0)*64+csw_st] = r4.x; CHB[(q_ld+1)*64+csw_st] = r4.y;
      CHB[(q_ld+2)*64+csw_st] = r4.z; CHB[(q_ld+3)*64+csw_st] = r4.w;
      if (cb < 3)
        r4 = *(const float4*)&XR[qbase + (size_t)c_ld*HW + ((cb+1) << 5) + q_ld];
      __syncthreads();
      int vb = cb << 5;
      for (int vv = 0; vv < 32; ++vv) {
        int v = vb + vv;
        float m0 = ST[SW(v, ul)];
        float m1 = ST[SW(v, ul+64)];
        int cs = c0 ^ (((vv >> 2) & 7) << 3);
        const float4 xa = *(const float4*)&CHB[vv*64 + cs];
        const float4 xb = *(const float4*)&CHB[vv*64 + cs + 4];
        acc0[0]=fmaf(m0,xa.x,acc0[0]); acc0[1]=fmaf(m0,xa.y,acc0[1]);
        acc0[2]=fmaf(m0,xa.z,acc0[2]); acc0[3]=fmaf(m0,xa.w,acc0[3]);
        acc0[4]=fmaf(m0,xb.x,acc0[4]); acc0[5]=fmaf(m0,xb.y,acc0[5]);
        acc0[6]=fmaf(m0,xb.z,acc0[6]); acc0[7]=fmaf(m0,xb.w,acc0[7]);
        acc1[0]=fmaf(m1,xa.x,acc1[0]); acc1[1]=fmaf(m1,xa.y,acc1[1]);
        acc1[2]=fmaf(m1,xa.z,acc1[2]); acc1[3]=fmaf(m1,xa.w,acc1[3]);
        acc1[4]=fmaf(m1,xb.x,acc1[4]); acc1[5]=fmaf(m1,xb.y,acc1[5]);
        acc1[6]=fmaf(m1,xb.z,acc1[6]); acc1[7]=fmaf(m1,xb.w,acc1[7]);
      }
    }
    float vl0 = Vl[ul], vl1 = Vl[ul+64];
    #pragma unroll
    for (int j = 0; j < 8; ++j) {
      size_t o0 = qbase + (size_t)(c0+j)*HW + ul;
      outL[o0]    = XL[o0]   *(1.f-vl0) + acc0[j]*vl0;
      outL[o0+64] = XL[o0+64]*(1.f-vl1) + acc1[j]*vl1;
    }
  }

  // ---- P6: out_right = xr*(1-Vr) + (M_lr @ xl)*Vr, xl in 8 KB v-chunks ----
  // M_lr[u,v] = ST[SW(u,v)] * Pu[v] * Qv[u]
  {
    float acc0[8], acc1[8];
    #pragma unroll
    for (int j = 0; j < 8; ++j) { acc0[j]=0.f; acc1[j]=0.f; }
    float qv_u0 = Qv[ul], qv_u1 = Qv[ul+64];
    float4 r4 = *(const float4*)&XL[qbase + (size_t)c_ld*HW + q_ld];  // chunk 0
    for (int cb = 0; cb < 4; ++cb) {
      __syncthreads();
      CHB[(q_ld+0)*64+csw_st] = r4.x; CHB[(q_ld+1)*64+csw_st] = r4.y;
      CHB[(q_ld+2)*64+csw_st] = r4.z; CHB[(q_ld+3)*64+csw_st] = r4.w;
      if (cb < 3)
        r4 = *(const float4*)&XL[qbase + (size_t)c_ld*HW + ((cb+1) << 5) + q_ld];
      __syncthreads();
      int qb = cb << 3;
      for (int lq = 0; lq < 8; ++lq) {
        const float4 s0 = *(const float4*)&ST[SWQ(ul,    qb+lq)];
        const float4 s1 = *(const float4*)&ST[SWQ(ul+64, qb+lq)];
        const float4 pu4 = *(const float4*)&Pu[(qb+lq) << 2];
        float sv0[4] = {s0.x, s0.y, s0.z, s0.w};
        float sv1[4] = {s1.x, s1.y, s1.z, s1.w};
        float pv[4]  = {pu4.x, pu4.y, pu4.z, pu4.w};
        int cs = c0 ^ ((lq & 7) << 3);
        #pragma unroll
        for (int k = 0; k < 4; ++k) {
          float m0 = sv0[k] * pv[k] * qv_u0;
          float m1 = sv1[k] * pv[k] * qv_u1;
          const float4 xa0 = *(const float4*)&CHB[((lq<<2)+k)*64 + cs];
          const float4 xb0 = *(const float4*)&CHB[((lq<<2)+k)*64 + cs + 4];
          acc0[0]=fmaf(m0,xa0.x,acc0[0]); acc0[1]=fmaf(m0,xa0.y,acc0[1]);
          acc0[2]=fmaf(m0,xa0.z,acc0[2]); acc0[3]=fmaf(m0,xa0.w,acc0[3]);
          acc0[4]=fmaf(m0,xb0.x,acc0[4]); acc0[5]=fmaf(m0,xb0.y,acc0[5]);
          acc0[6]=fmaf(m0,xb0.z,acc0[6]); acc0[7]=fmaf(m0,xb0.w,acc0[7]);
          acc1[0]=fmaf(m1,xa0.x,acc1[0]); acc1[1]=fmaf(m1,xa0.y,acc1[1]);
          acc1[2]=fmaf(m1,xa0.z,acc1[2]); acc1[3]=fmaf(m1,xa0.w,acc1[3]);
          acc1[4]=fmaf(m1,xb0.x,acc1[4]); acc1[5]=fmaf(m1,xb0.y,acc1[5]);
          acc1[6]=fmaf(m1,xb0.z,acc1[6]); acc1[7]=fmaf(m1,xb0.w,acc1[7]);
        }
      }
    }
    float vr0 = Vr[ul], vr1 = Vr[ul+64];
    // hand-batched epilogue: all XR loads first, then all outR stores
    // (K aliases outR; explicit ordering removes any aliasing serialization)
    float xr0[8], xr1[8];
    #pragma unroll
    for (int j = 0; j < 8; ++j) {
      size_t o0 = qbase + (size_t)(c0+j)*HW + ul;
      xr0[j] = XR[o0];
      xr1[j] = XR[o0+64];
    }
    #pragma unroll
    for (int j = 0; j < 8; ++j) {
      size_t o0 = qbase + (size_t)(c0+j)*HW + ul;
      outR[o0]    = xr0[j]*(1.f-vr0) + acc0[j]*vr0;
      outR[o0+64] = xr1[j]*(1.f-vr1) + acc1[j]*vr1;
    }
  }
}

extern "C" void kernel_launch(void* const* d_in, const int* in_sizes, int n_in,
                              void* d_out, int out_size, void* d_ws, size_t ws_size,
                              hipStream_t stream) {
  const float* xL    = (const float*)d_in[0];
  const float* xR    = (const float*)d_in[1];
  const float* gamma = (const float*)d_in[2];
  const float* beta  = (const float*)d_in[3];
  const float* rw1   = (const float*)d_in[4];
  const float* rb1   = (const float*)d_in[5];
  const float* rw2   = (const float*)d_in[6];
  const float* rb2   = (const float*)d_in[7];
  const float* qw    = (const float*)d_in[8];
  const float* qb    = (const float*)d_in[9];
  const float* kw    = (const float*)d_in[10];
  const float* kb    = (const float*)d_in[11];
  float* out = (float*)d_out;
  char* ws = (char*)d_ws;

  const size_t BUF = (size_t)BB*CH_N*HW*4;   // 33,554,432 bytes
  float* y1L  = (float*)(ws);                // B0
  float* y1R  = (float*)(ws + BUF);          // B1
  float* Qb   = (float*)(ws + 2*BUF);        // B2: Q
  float* sums = (float*)(ws + 3*BUF);        // 256 floats
  float* ss   = sums + 256;                  // 256 floats
  float* rsL  = sums + 512;                  // 8*64*128 floats
  float* rsR  = rsL + (size_t)BB*CH_N*HH;

  // K lives in d_out's right half (= outR). Safe: pam block (b,h) reads its
  // K rows in P1 strictly before writing the same rows in P6.
  float* Kb = out + (size_t)BB*CH_N*HW;

  hipMemsetAsync(sums, 0, (512 + 2*(size_t)BB*CH_N*HH)*sizeof(float), stream);
  k_stats<<<512, 256, 0, stream>>>(xL, xR, sums);
  k_finalize<<<1, 128, 0, stream>>>(sums, gamma, beta, ss);

  dim3 cg(64, 4, 16);
  k_conv<0><<<cg, 256, 0, stream>>>(xL, xR, xL, xR, rw1, rb1, ss, y1L, y1R,
                                    nullptr, nullptr, nullptr, nullptr, nullptr, nullptr);
  k_conv<1><<<cg, 256, 0, stream>>>(y1L, y1R, xL, xR, rw2, rb2, ss, Qb, Kb,
                                    qw, qb, kw, kb, rsL, rsR);

  const int SMEM = 19464 * 4;   // 77,856 B -> 2 blocks/CU
  hipFuncSetAttribute((const void*)k_pam, hipFuncAttributeMaxDynamicSharedMemorySize, SMEM);
  k_pam<<<1024, 512, SMEM, stream>>>(Qb, Kb, xL, xR, out, Kb, rsL, rsR);
}